// Round 2
// baseline (360.887 us; speedup 1.0000x reference)
//
#include <hip/hip_runtime.h>

// SimpleGNN on MI355X — fp32 in/out, edge_index int32-or-int64 (auto-detected).
// Algebra: out[d] = di[d]*(S[d] @ M) + di[d]*cnt_col[d]*c + b2
//   M = W1^T @ W2^T [128 x 64], c = b1 @ W2^T [64]
//   S[d] = sum_{e: col_e = d} x[row_e]
//   di[d] = deg_row[d] > 0 ? 1/deg_row[d] : 0   (deg_row = bincount of row)
// Implemented as y = x @ M [N x 64] fp32, then per-edge scatter-add of y rows.

#define IN_CH   128
#define OUT_CH  64

// -------- kernel 0: detect int64 vs int32 edge_index --------
// int64 values < 2^31 => every odd int32 word of the buffer is 0.
__global__ void mk_flag(const int* __restrict__ ei, int* __restrict__ flag) {
    if (blockIdx.x == 0 && threadIdx.x == 0) {
        int f = 1;
        for (int i = 1; i < 64; i += 2)
            if (ei[i] != 0) { f = 0; break; }
        *flag = f;   // 1 = int64 (stride 2), 0 = int32 (stride 1)
    }
}

// -------- kernel 1: M = W1^T W2^T, c = b1 @ W2^T --------
__global__ __launch_bounds__(256) void mk_M_c(const float* __restrict__ W1,
                                              const float* __restrict__ b1,
                                              const float* __restrict__ W2,
                                              float* __restrict__ M,   // [128*64]
                                              float* __restrict__ c) { // [64]
    int tid = blockIdx.x * blockDim.x + threadIdx.x;
    if (tid < IN_CH * OUT_CH) {
        int o = tid & (OUT_CH - 1);
        int i = tid >> 6;
        float acc = 0.f;
        for (int h = 0; h < 128; ++h)
            acc += W1[h * 128 + i] * W2[o * 128 + h];
        M[i * OUT_CH + o] = acc;
    } else if (tid < IN_CH * OUT_CH + OUT_CH) {
        int o = tid - IN_CH * OUT_CH;
        float acc = 0.f;
        for (int h = 0; h < 128; ++h)
            acc += b1[h] * W2[o * 128 + h];
        c[o] = acc;
    }
}

// -------- kernel 2: degree counts --------
__global__ __launch_bounds__(256) void mk_deg(const int* __restrict__ ei,
                                              const int* __restrict__ flag,
                                              int* __restrict__ deg_row,
                                              int* __restrict__ cnt_col,
                                              int n_edges, int n_nodes) {
    int e = blockIdx.x * blockDim.x + threadIdx.x;
    if (e >= n_edges) return;
    int stride = 1 + *flag;
    int r = ei[(size_t)e * stride];
    int c = ei[((size_t)n_edges + e) * stride];
    if ((unsigned)r < (unsigned)n_nodes) atomicAdd(&deg_row[r], 1);
    if ((unsigned)c < (unsigned)n_nodes) atomicAdd(&cnt_col[c], 1);
}

// -------- kernel 3: y = x @ M (fp32) --------
#define GEMM_ROWS 32
__global__ __launch_bounds__(256) void mk_y(const float* __restrict__ x,
                                            const float* __restrict__ M,
                                            float* __restrict__ y,
                                            int n_nodes) {
    __shared__ float Ms[IN_CH * OUT_CH];      // 32 KB
    __shared__ float xs[GEMM_ROWS][IN_CH];    // 16 KB
    int tid = threadIdx.x;
    for (int k = tid; k < IN_CH * OUT_CH; k += 256) Ms[k] = M[k];

    int o = tid & 63;
    int rbase = tid >> 6;   // 0..3

    int row0 = blockIdx.x * GEMM_ROWS;
    if (row0 >= n_nodes) return;
    int nrows = n_nodes - row0;
    if (nrows > GEMM_ROWS) nrows = GEMM_ROWS;

    __syncthreads();  // Ms visible
    // stage x tile as float4
    const float4* xv = (const float4*)(x + (size_t)row0 * IN_CH);
    float4* xsv = (float4*)&xs[0][0];
    int n4 = nrows * (IN_CH / 4);
    for (int k = tid; k < n4; k += 256) xsv[k] = xv[k];
    __syncthreads();

    for (int r = rbase; r < nrows; r += 4) {
        float acc = 0.f;
#pragma unroll
        for (int i = 0; i < IN_CH; ++i)
            acc += xs[r][i] * Ms[i * OUT_CH + o];
        y[(size_t)(row0 + r) * OUT_CH + o] = acc;
    }
}

// -------- kernel 4: scatter-add y rows by dst --------
__global__ __launch_bounds__(256) void mk_scatter(const int* __restrict__ ei,
                                                  const int* __restrict__ flag,
                                                  const float* __restrict__ y,
                                                  float* __restrict__ agg,
                                                  int n_edges, int n_nodes) {
    int gid = blockIdx.x * blockDim.x + threadIdx.x;
    int e = gid >> 6;
    int lane = gid & 63;
    if (e >= n_edges) return;
    int stride = 1 + *flag;
    int s = ei[(size_t)e * stride];
    int d = ei[((size_t)n_edges + e) * stride];
    if ((unsigned)s >= (unsigned)n_nodes || (unsigned)d >= (unsigned)n_nodes) return;
    float v = y[(size_t)s * OUT_CH + lane];
    atomicAdd(&agg[(size_t)d * OUT_CH + lane], v);
}

// -------- kernel 5: finalize --------
__global__ __launch_bounds__(256) void mk_final(const float* __restrict__ agg,
                                                const int* __restrict__ deg_row,
                                                const int* __restrict__ cnt_col,
                                                const float* __restrict__ c,
                                                const float* __restrict__ b2,
                                                float* __restrict__ out,
                                                int n_nodes) {
    int idx = blockIdx.x * blockDim.x + threadIdx.x;
    if (idx >= n_nodes * OUT_CH) return;
    int n = idx >> 6;
    int o = idx & 63;
    int dr = deg_row[n];
    float di = (dr > 0) ? (1.0f / (float)dr) : 0.0f;
    out[idx] = di * agg[idx] + di * (float)cnt_col[n] * c[o] + b2[o];
}

extern "C" void kernel_launch(void* const* d_in, const int* in_sizes, int n_in,
                              void* d_out, int out_size, void* d_ws, size_t ws_size,
                              hipStream_t stream) {
    const float* x  = (const float*)d_in[0];
    const int*   ei = (const int*)d_in[1];
    const float* W1 = (const float*)d_in[2];
    const float* b1 = (const float*)d_in[3];
    const float* W2 = (const float*)d_in[4];
    const float* b2 = (const float*)d_in[5];
    float* out = (float*)d_out;

    const int n_nodes = in_sizes[0] / IN_CH;     // 50000
    const int n_edges = in_sizes[1] / 2;         // 800000

    // workspace layout
    char* ws = (char*)d_ws;
    float* M       = (float*)(ws);                 // 32768 B
    float* c       = (float*)(ws + 32768);         // 256 B
    int*   flag    = (int*)  (ws + 33024);         // 128 B
    int*   deg_row = (int*)  (ws + 33152);         // 200064 B
    int*   cnt_col = (int*)  (ws + 233216);        // 200064 B
    float* y       = (float*)(ws + 433280);        // 12.8 MB
    float* agg     = (float*)(ws + 433280 + (size_t)n_nodes * OUT_CH * 4);

    // zero deg_row + cnt_col (contiguous) and agg
    hipMemsetAsync(deg_row, 0, 2 * 200064, stream);
    hipMemsetAsync(agg, 0, (size_t)n_nodes * OUT_CH * sizeof(float), stream);

    mk_flag<<<1, 64, 0, stream>>>(ei, flag);

    mk_M_c<<<(IN_CH * OUT_CH + OUT_CH + 255) / 256, 256, 0, stream>>>(W1, b1, W2, M, c);

    mk_deg<<<(n_edges + 255) / 256, 256, 0, stream>>>(ei, flag, deg_row, cnt_col,
                                                      n_edges, n_nodes);

    int gemm_blocks = (n_nodes + GEMM_ROWS - 1) / GEMM_ROWS;
    mk_y<<<gemm_blocks, 256, 0, stream>>>(x, M, y, n_nodes);

    long long scatter_threads = (long long)n_edges * 64;
    int scatter_blocks = (int)((scatter_threads + 255) / 256);
    mk_scatter<<<scatter_blocks, 256, 0, stream>>>(ei, flag, y, agg, n_edges, n_nodes);

    mk_final<<<(n_nodes * OUT_CH + 255) / 256, 256, 0, stream>>>(agg, deg_row, cnt_col,
                                                                 c, b2, out, n_nodes);
}

// Round 3
// 265.347 us; speedup vs baseline: 1.3601x; 1.3601x over previous
//
#include <hip/hip_runtime.h>

// SimpleGNN on MI355X — fp32 in/out, edge_index int32/int64 auto-detect.
// out[d] = di[d]*(S[d] @ M) + di[d]*cnt_col[d]*c + b2
//   M = W1^T W2^T [128x64], c = b1 @ W2^T [64]
//   S[d] = sum_{e: col_e=d} x[row_e],  di[d] = 1/deg_row[d] (0 if deg 0)
// y = x@M [N x 64] fp32 (micro-tiled), CSR-by-dst gather-sum (no fp32 atomics).

#define IN_CH   128
#define OUT_CH  64
#define SCAN_B  256

// -------- kernel 1: M = W1^T W2^T, c = b1 @ W2^T, + int64-detect flag --------
__global__ __launch_bounds__(256) void mk_M_c(const float* __restrict__ W1,
                                              const float* __restrict__ b1,
                                              const float* __restrict__ W2,
                                              const int* __restrict__ ei,
                                              float* __restrict__ M,   // [128*64]
                                              float* __restrict__ c,   // [64]
                                              int* __restrict__ flag) {
    int tid = blockIdx.x * blockDim.x + threadIdx.x;
    if (tid < IN_CH * OUT_CH) {
        int o = tid & (OUT_CH - 1);
        int i = tid >> 6;
        float acc = 0.f;
        for (int h = 0; h < 128; ++h)
            acc += W1[h * 128 + i] * W2[o * 128 + h];
        M[i * OUT_CH + o] = acc;
    } else if (tid < IN_CH * OUT_CH + OUT_CH) {
        int o = tid - IN_CH * OUT_CH;
        float acc = 0.f;
        for (int h = 0; h < 128; ++h)
            acc += b1[h] * W2[o * 128 + h];
        c[o] = acc;
    } else if (tid == IN_CH * OUT_CH + OUT_CH) {
        // int64 edge_index => odd int32 words are all 0 (values < 2^31)
        int f = 1;
        for (int i = 1; i < 64; i += 2)
            if (ei[i] != 0) { f = 0; break; }
        *flag = f;   // 1 = int64 (stride 2), 0 = int32
    }
}

// -------- kernel 2: degree counts (int atomics, small) --------
__global__ __launch_bounds__(256) void mk_deg(const int* __restrict__ ei,
                                              const int* __restrict__ flag,
                                              int* __restrict__ deg_row,
                                              int* __restrict__ cnt_col,
                                              int n_edges, int n_nodes) {
    int e = blockIdx.x * blockDim.x + threadIdx.x;
    if (e >= n_edges) return;
    int stride = 1 + *flag;
    int r = ei[(size_t)e * stride];
    int c = ei[((size_t)n_edges + e) * stride];
    bool rv = (unsigned)r < (unsigned)n_nodes;
    bool cv = (unsigned)c < (unsigned)n_nodes;
    if (rv) atomicAdd(&deg_row[r], 1);
    if (rv && cv) atomicAdd(&cnt_col[c], 1);   // edge "valid" iff both in range
}

// -------- scan: exclusive prefix sum of cnt_col -> cursor --------
__global__ __launch_bounds__(SCAN_B) void scanA(const int* __restrict__ cnt,
                                                int* __restrict__ cursor,
                                                int* __restrict__ bsums, int n) {
    __shared__ int s[SCAN_B];
    int t = threadIdx.x;
    int i = blockIdx.x * SCAN_B + t;
    int v = (i < n) ? cnt[i] : 0;
    s[t] = v;
    __syncthreads();
    for (int d = 1; d < SCAN_B; d <<= 1) {
        int add = (t >= d) ? s[t - d] : 0;
        __syncthreads();
        s[t] += add;
        __syncthreads();
    }
    if (i < n) cursor[i] = s[t] - v;              // block-local exclusive
    if (t == SCAN_B - 1) bsums[blockIdx.x] = s[t];
}

__global__ __launch_bounds__(SCAN_B) void scanB(int* __restrict__ bsums, int nb) {
    int t = threadIdx.x;
    if (nb > SCAN_B) {       // fallback (not hit for n=50000)
        if (t == 0) {
            int run = 0;
            for (int j = 0; j < nb; ++j) { int x = bsums[j]; bsums[j] = run; run += x; }
        }
        return;
    }
    __shared__ int s[SCAN_B];
    int v = (t < nb) ? bsums[t] : 0;
    s[t] = v;
    __syncthreads();
    for (int d = 1; d < SCAN_B; d <<= 1) {
        int add = (t >= d) ? s[t - d] : 0;
        __syncthreads();
        s[t] += add;
        __syncthreads();
    }
    if (t < nb) bsums[t] = s[t] - v;              // exclusive block offsets
}

__global__ __launch_bounds__(SCAN_B) void scanC(int* __restrict__ cursor,
                                                const int* __restrict__ bsums, int n) {
    int i = blockIdx.x * SCAN_B + threadIdx.x;
    if (i < n) cursor[i] += bsums[blockIdx.x];
}

// -------- CSR fill: csr_src[slot] = src, slot = cursor[dst]++ --------
__global__ __launch_bounds__(256) void mk_fill(const int* __restrict__ ei,
                                               const int* __restrict__ flag,
                                               int* __restrict__ cursor,
                                               int* __restrict__ csr_src,
                                               int n_edges, int n_nodes) {
    int e = blockIdx.x * blockDim.x + threadIdx.x;
    if (e >= n_edges) return;
    int stride = 1 + *flag;
    int s = ei[(size_t)e * stride];
    int d = ei[((size_t)n_edges + e) * stride];
    if ((unsigned)s >= (unsigned)n_nodes || (unsigned)d >= (unsigned)n_nodes) return;
    int slot = atomicAdd(&cursor[d], 1);
    csr_src[slot] = s;
}

// -------- kernel: y = x @ M, 64x64 tile, 4x4 register micro-tile --------
__global__ __launch_bounds__(256) void mk_y(const float* __restrict__ x,
                                            const float* __restrict__ M,
                                            float* __restrict__ y,
                                            int n_nodes) {
    __shared__ float Ms[IN_CH * OUT_CH];   // 32 KB, [k][o] layout (natural)
    __shared__ float xs[64][IN_CH + 4];    // +4 pad: breaks bank aliasing, keeps 16B align
    int tid = threadIdx.x;
    int tx = tid & 15;        // col group: 4*tx .. 4*tx+3
    int ty = tid >> 4;        // row group: 4*ty .. 4*ty+3
    int row0 = blockIdx.x * 64;

    // stage M (8192 floats as float4)
    const float4* Mv = (const float4*)M;
    float4* Msv = (float4*)Ms;
#pragma unroll
    for (int k = 0; k < 8; ++k) Msv[tid + 256 * k] = Mv[tid + 256 * k];

    // stage x tile (64 rows x 128, zero-padded past n_nodes)
    for (int f = tid; f < 64 * 32; f += 256) {
        int r = f >> 5, kq = f & 31;
        float4 v = make_float4(0.f, 0.f, 0.f, 0.f);
        if (row0 + r < n_nodes)
            v = *(const float4*)&x[(size_t)(row0 + r) * IN_CH + 4 * kq];
        *(float4*)&xs[r][4 * kq] = v;
    }
    __syncthreads();

    float4 acc[4];
#pragma unroll
    for (int j = 0; j < 4; ++j) acc[j] = make_float4(0.f, 0.f, 0.f, 0.f);

    for (int k = 0; k < IN_CH; k += 4) {
        float4 xr[4], mr[4];
#pragma unroll
        for (int j = 0; j < 4; ++j)
            xr[j] = *(const float4*)&xs[4 * ty + j][k];
#pragma unroll
        for (int kk = 0; kk < 4; ++kk)
            mr[kk] = *(const float4*)&Ms[(k + kk) * OUT_CH + 4 * tx];
#pragma unroll
        for (int j = 0; j < 4; ++j) {
            acc[j].x = fmaf(xr[j].x, mr[0].x, acc[j].x);
            acc[j].y = fmaf(xr[j].x, mr[0].y, acc[j].y);
            acc[j].z = fmaf(xr[j].x, mr[0].z, acc[j].z);
            acc[j].w = fmaf(xr[j].x, mr[0].w, acc[j].w);
            acc[j].x = fmaf(xr[j].y, mr[1].x, acc[j].x);
            acc[j].y = fmaf(xr[j].y, mr[1].y, acc[j].y);
            acc[j].z = fmaf(xr[j].y, mr[1].z, acc[j].z);
            acc[j].w = fmaf(xr[j].y, mr[1].w, acc[j].w);
            acc[j].x = fmaf(xr[j].z, mr[2].x, acc[j].x);
            acc[j].y = fmaf(xr[j].z, mr[2].y, acc[j].y);
            acc[j].z = fmaf(xr[j].z, mr[2].z, acc[j].z);
            acc[j].w = fmaf(xr[j].z, mr[2].w, acc[j].w);
            acc[j].x = fmaf(xr[j].w, mr[3].x, acc[j].x);
            acc[j].y = fmaf(xr[j].w, mr[3].y, acc[j].y);
            acc[j].z = fmaf(xr[j].w, mr[3].z, acc[j].z);
            acc[j].w = fmaf(xr[j].w, mr[3].w, acc[j].w);
        }
    }

#pragma unroll
    for (int j = 0; j < 4; ++j) {
        int r = row0 + 4 * ty + j;
        if (r < n_nodes)
            *(float4*)&y[(size_t)r * OUT_CH + 4 * tx] = acc[j];
    }
}

// -------- gather-sum + finalize: one wave per dst node --------
__global__ __launch_bounds__(256) void mk_agg_final(const int* __restrict__ cursor, // end offsets
                                                    const int* __restrict__ cnt_col,
                                                    const int* __restrict__ csr_src,
                                                    const int* __restrict__ deg_row,
                                                    const float* __restrict__ y,
                                                    const float* __restrict__ c,
                                                    const float* __restrict__ b2,
                                                    float* __restrict__ out,
                                                    int n_nodes) {
    int wave = threadIdx.x >> 6;
    int lane = threadIdx.x & 63;
    int d = blockIdx.x * 4 + wave;
    if (d >= n_nodes) return;
    int end = cursor[d];          // after fill, cursor[d] = start + cnt
    int cnt = cnt_col[d];
    int start = end - cnt;
    float acc = 0.f;
    int j = start;
    for (; j + 3 < end; j += 4) {
        int s0 = csr_src[j];
        int s1 = csr_src[j + 1];
        int s2 = csr_src[j + 2];
        int s3 = csr_src[j + 3];
        float v0 = y[(size_t)s0 * OUT_CH + lane];
        float v1 = y[(size_t)s1 * OUT_CH + lane];
        float v2 = y[(size_t)s2 * OUT_CH + lane];
        float v3 = y[(size_t)s3 * OUT_CH + lane];
        acc += (v0 + v1) + (v2 + v3);
    }
    for (; j < end; ++j)
        acc += y[(size_t)csr_src[j] * OUT_CH + lane];
    int dr = deg_row[d];
    float di = (dr > 0) ? (1.0f / (float)dr) : 0.f;
    out[(size_t)d * OUT_CH + lane] = di * acc + di * (float)cnt * c[lane] + b2[lane];
}

extern "C" void kernel_launch(void* const* d_in, const int* in_sizes, int n_in,
                              void* d_out, int out_size, void* d_ws, size_t ws_size,
                              hipStream_t stream) {
    const float* x  = (const float*)d_in[0];
    const int*   ei = (const int*)d_in[1];
    const float* W1 = (const float*)d_in[2];
    const float* b1 = (const float*)d_in[3];
    const float* W2 = (const float*)d_in[4];
    const float* b2 = (const float*)d_in[5];
    float* out = (float*)d_out;

    const int n_nodes = in_sizes[0] / IN_CH;     // 50000
    const int n_edges = in_sizes[1] / 2;         // 800000

    // workspace layout
    char* ws = (char*)d_ws;
    float* M       = (float*)(ws);                 // 32768
    float* c       = (float*)(ws + 32768);         // 256
    int*   flag    = (int*)  (ws + 33024);         // 128
    int*   deg_row = (int*)  (ws + 33152);         // 200064
    int*   cnt_col = (int*)  (ws + 233216);        // 200064
    int*   cursor  = (int*)  (ws + 433280);        // 200064
    int*   bsums   = (int*)  (ws + 633344);        // 1024
    int*   csr_src = (int*)  (ws + 634368);        // 3.2 MB
    float* y       = (float*)(ws + 634368 + (size_t)n_edges * 4);

    // zero deg_row + cnt_col (contiguous)
    hipMemsetAsync(deg_row, 0, 2 * 200064, stream);

    mk_M_c<<<(IN_CH * OUT_CH + OUT_CH + 1 + 255) / 256, 256, 0, stream>>>(
        W1, b1, W2, ei, M, c, flag);

    mk_deg<<<(n_edges + 255) / 256, 256, 0, stream>>>(ei, flag, deg_row, cnt_col,
                                                      n_edges, n_nodes);

    int nb = (n_nodes + SCAN_B - 1) / SCAN_B;    // 196
    scanA<<<nb, SCAN_B, 0, stream>>>(cnt_col, cursor, bsums, n_nodes);
    scanB<<<1, SCAN_B, 0, stream>>>(bsums, nb);
    scanC<<<nb, SCAN_B, 0, stream>>>(cursor, bsums, n_nodes);

    mk_fill<<<(n_edges + 255) / 256, 256, 0, stream>>>(ei, flag, cursor, csr_src,
                                                       n_edges, n_nodes);

    mk_y<<<(n_nodes + 63) / 64, 256, 0, stream>>>(x, M, y, n_nodes);

    mk_agg_final<<<(n_nodes + 3) / 4, 256, 0, stream>>>(cursor, cnt_col, csr_src,
                                                        deg_row, y, c, b2, out, n_nodes);
}